// Round 4
// baseline (516.096 us; speedup 1.0000x reference)
//
#include <hip/hip_runtime.h>

// Problem constants (fixed by the reference)
#define BB 4
#define NS 4096
#define NT 4096
#define FS 256
#define FT 256
#define FO 64
#define ALPHA 0.2f
#define OUT_SLOPE 0.01f
#define JSPLIT 4   // j-range split across blocks (partials combined in k_fin)

typedef __attribute__((ext_vector_type(8))) short short8;
typedef __attribute__((ext_vector_type(4))) float floatx4;
typedef __attribute__((ext_vector_type(4))) int int4v;

__device__ __forceinline__ float leaky_max(float x, float s) { return fmaxf(x, s * x); }

// fp32 -> bf16 round-to-nearest-even
__device__ __forceinline__ short f2bf(float x) {
  union { float f; unsigned u; } c; c.f = x;
  unsigned r = c.u + 0x7fffu + ((c.u >> 16) & 1u);
  return (short)(r >> 16);
}

// Fused: wa[f] = Wt[f,:] @ a[64:] (redundant per block, LDS) then
// t[row] = h[row,:] @ wa.  256 blocks x 64 rows.
__global__ __launch_bounds__(256) void k_pre(const float* __restrict__ Wt,
                                             const float* __restrict__ a,
                                             const float* __restrict__ h,
                                             float* __restrict__ tvec) {
  __shared__ __align__(16) float wa[256];
  const int tid = threadIdx.x;
  {
    float acc = 0.f;
#pragma unroll 8
    for (int o = 0; o < FO; ++o) acc += Wt[tid * FO + o] * a[FO + o];
    wa[tid] = acc;
  }
  __syncthreads();
  const int lane = tid & 63, wv = tid >> 6;
  const float4 w4 = ((const float4*)wa)[lane];
#pragma unroll 4
  for (int rr = 0; rr < 16; ++rr) {
    const int row = blockIdx.x * 64 + wv * 16 + rr;
    const float4 hv = ((const float4*)(h + (size_t)row * FT))[lane];
    float acc = hv.x * w4.x + hv.y * w4.y + hv.z * w4.z + hv.w * w4.w;
#pragma unroll
    for (int off = 32; off; off >>= 1) acc += __shfl_down(acc, off);
    if (lane == 0) tvec[row] = acc;
  }
}

// per-batch max of t (softmax shift; any per-row-valid upper bound works)
__global__ __launch_bounds__(256) void k_tmax(const float* __restrict__ tvec,
                                              float* __restrict__ tmax) {
  __shared__ float red[256];
  int b = blockIdx.x, tid = threadIdx.x;
  float m = -3.0e38f;
  for (int j = tid; j < NS; j += 256) m = fmaxf(m, tvec[b * NS + j]);
  red[tid] = m;
  __syncthreads();
  for (int s = 128; s; s >>= 1) {
    if (tid < s) red[tid] = fmaxf(red[tid], red[tid + s]);
    __syncthreads();
  }
  if (tid == 0) tmax[b] = red[0];
}

// Ws_ctx = ctx @ Ws; writes TRANSPOSED bf16 vT[b][f][row] (MFMA B-operand feed)
// and s[row] = Ws_ctx[row,:] @ a[:64].  One wave per 4 rows, 64 lanes = f.
__global__ __launch_bounds__(256) void k_wsctx(const float* __restrict__ ctx,
                                               const float* __restrict__ Ws,
                                               const float* __restrict__ a,
                                               short* __restrict__ vT,
                                               float* __restrict__ svec) {
  const int f = threadIdx.x & 63, wave = threadIdx.x >> 6;
  const int row0 = blockIdx.x * 16 + wave * 4;  // global row in [0, B*NS)
  const float4* c0 = (const float4*)(ctx + (size_t)(row0 + 0) * FS);
  const float4* c1 = (const float4*)(ctx + (size_t)(row0 + 1) * FS);
  const float4* c2 = (const float4*)(ctx + (size_t)(row0 + 2) * FS);
  const float4* c3 = (const float4*)(ctx + (size_t)(row0 + 3) * FS);
  float r0 = 0.f, r1 = 0.f, r2 = 0.f, r3 = 0.f;
#pragma unroll 2
  for (int k4 = 0; k4 < FS / 4; ++k4) {
    const float w0 = Ws[(k4 * 4 + 0) * FO + f];
    const float w1 = Ws[(k4 * 4 + 1) * FO + f];
    const float w2 = Ws[(k4 * 4 + 2) * FO + f];
    const float w3 = Ws[(k4 * 4 + 3) * FO + f];
    float4 x;
    x = c0[k4]; r0 += x.x * w0 + x.y * w1 + x.z * w2 + x.w * w3;
    x = c1[k4]; r1 += x.x * w0 + x.y * w1 + x.z * w2 + x.w * w3;
    x = c2[k4]; r2 += x.x * w0 + x.y * w1 + x.z * w2 + x.w * w3;
    x = c3[k4]; r3 += x.x * w0 + x.y * w1 + x.z * w2 + x.w * w3;
  }
  const int b = row0 >> 12;             // NS = 4096 rows per batch
  const int rloc = row0 & (NS - 1);
  short* vp = vT + ((size_t)b * FO + f) * NS + rloc;
  vp[0] = f2bf(r0); vp[1] = f2bf(r1); vp[2] = f2bf(r2); vp[3] = f2bf(r3);

  const float af = a[f];
  float s0 = r0 * af, s1 = r1 * af, s2 = r2 * af, s3 = r3 * af;
#pragma unroll
  for (int off = 32; off; off >>= 1) {
    s0 += __shfl_down(s0, off);
    s1 += __shfl_down(s1, off);
    s2 += __shfl_down(s2, off);
    s3 += __shfl_down(s3, off);
  }
  if (f == 0) {
    svec[row0 + 0] = s0;
    svec[row0 + 1] = s1;
    svec[row0 + 2] = s2;
    svec[row0 + 3] = s3;
  }
}

// MFMA partial attention: each wave owns 16 rows, computes w on the fly
// (A-frag = 8 consecutive j per lane, generated in-register; no LDS),
// B-frag = 16B contiguous load from vT.  adj streamed with nontemporal loads
// (read-once; keep L2 for vT).  Partials per j-split, no atomics.
__global__ __launch_bounds__(256) void k_part(const int* __restrict__ adj,
                                              const short* __restrict__ vT,
                                              const float* __restrict__ svec,
                                              const float* __restrict__ tvec,
                                              const float* __restrict__ tmax,
                                              float* __restrict__ outpart,
                                              float* __restrict__ lpart) {
  const int lane = threadIdx.x & 63;
  const int wv = threadIdx.x >> 6;   // 0..3
  const int m = lane & 15;           // A row within 16 / B,D col (f within 16)
  const int q = lane >> 4;           // quad: k-offset q*8

  const int tile = blockIdx.x >> 2;      // 256 row-tiles of 64
  const int js = blockIdx.x & (JSPLIT - 1);
  const int b = tile >> 6;               // 64 tiles per batch
  const int i0 = (tile & 63) * 64;
  const int jbase = js * (NS / JSPLIT);

  const int r = i0 + wv * 16 + m;        // this lane's target row (within batch)
  const float sr = svec[b * NS + r];
  const float cr = leaky_max(sr + tmax[b], ALPHA);

  const int* arow = adj + ((size_t)(b * NT) + r) * NS + jbase;
  const float* tp = tvec + b * NS + jbase;
  const short* vp0 = vT + ((size_t)b * FO + m) * NS + jbase;  // + ft*16*NS

  floatx4 acc0 = {0.f, 0.f, 0.f, 0.f};
  floatx4 acc1 = {0.f, 0.f, 0.f, 0.f};
  floatx4 acc2 = {0.f, 0.f, 0.f, 0.f};
  floatx4 acc3 = {0.f, 0.f, 0.f, 0.f};
  float lsum = 0.f;

#pragma unroll 4
  for (int jc = 0; jc < (NS / JSPLIT) / 32; ++jc) {
    const int j0 = jc * 32 + q * 8;
    const int4v a0 = __builtin_nontemporal_load((const int4v*)(arow + j0));
    const int4v a1 = __builtin_nontemporal_load((const int4v*)(arow + j0 + 4));
    const float4 t0 = *(const float4*)(tp + j0);
    const float4 t1 = *(const float4*)(tp + j0 + 4);

    float w[8];
    w[0] = (a0.x > 0) ? __expf(leaky_max(sr + t0.x, ALPHA) - cr) : 0.f;
    w[1] = (a0.y > 0) ? __expf(leaky_max(sr + t0.y, ALPHA) - cr) : 0.f;
    w[2] = (a0.z > 0) ? __expf(leaky_max(sr + t0.z, ALPHA) - cr) : 0.f;
    w[3] = (a0.w > 0) ? __expf(leaky_max(sr + t0.w, ALPHA) - cr) : 0.f;
    w[4] = (a1.x > 0) ? __expf(leaky_max(sr + t1.x, ALPHA) - cr) : 0.f;
    w[5] = (a1.y > 0) ? __expf(leaky_max(sr + t1.y, ALPHA) - cr) : 0.f;
    w[6] = (a1.z > 0) ? __expf(leaky_max(sr + t1.z, ALPHA) - cr) : 0.f;
    w[7] = (a1.w > 0) ? __expf(leaky_max(sr + t1.w, ALPHA) - cr) : 0.f;

    lsum += ((w[0] + w[1]) + (w[2] + w[3])) + ((w[4] + w[5]) + (w[6] + w[7]));

    short8 af;
#pragma unroll
    for (int i = 0; i < 8; ++i) af[i] = f2bf(w[i]);

    const short8 bf0 = *(const short8*)(vp0 + 0 * 16 * NS + j0);
    const short8 bf1 = *(const short8*)(vp0 + 1 * 16 * NS + j0);
    const short8 bf2 = *(const short8*)(vp0 + 2 * 16 * NS + j0);
    const short8 bf3 = *(const short8*)(vp0 + 3 * 16 * NS + j0);
    acc0 = __builtin_amdgcn_mfma_f32_16x16x32_bf16(af, bf0, acc0, 0, 0, 0);
    acc1 = __builtin_amdgcn_mfma_f32_16x16x32_bf16(af, bf1, acc1, 0, 0, 0);
    acc2 = __builtin_amdgcn_mfma_f32_16x16x32_bf16(af, bf2, acc2, 0, 0, 0);
    acc3 = __builtin_amdgcn_mfma_f32_16x16x32_bf16(af, bf3, acc3, 0, 0, 0);
  }

  // denominator partial: reduce lsum over the 4 quads holding the same row m
  float v = lsum;
  v += __shfl_down(v, 32);
  v += __shfl_down(v, 16);
  if (lane < 16) lpart[(size_t)js * BB * NT + (size_t)b * NT + i0 + wv * 16 + m] = v;

  // numerator partial: D layout col=lane&15, row=(lane>>4)*4+reg
  float* op = outpart + (size_t)js * BB * NT * FO +
              ((size_t)(b * NT) + i0 + wv * 16 + q * 4) * FO + m;
#pragma unroll
  for (int reg = 0; reg < 4; ++reg) {
    op[(size_t)reg * FO + 0 * 16] = acc0[reg];
    op[(size_t)reg * FO + 1 * 16] = acc1[reg];
    op[(size_t)reg * FO + 2 * 16] = acc2[reg];
    op[(size_t)reg * FO + 3 * 16] = acc3[reg];
  }
}

// out[i,f] = leaky( (sum_js outpart) / (sum_js lpart), 0.01 ), float4-vectorized
__global__ __launch_bounds__(256) void k_fin(const float* __restrict__ outpart,
                                             const float* __restrict__ lpart,
                                             float* __restrict__ out) {
  const size_t NP = (size_t)BB * NT * FO;   // floats per partial
  const int idx = blockIdx.x * 256 + threadIdx.x;   // float4 index
  const int row = idx >> 4;                          // 16 float4 per row
  float l = lpart[row] + lpart[BB * NT + row] + lpart[2 * BB * NT + row] +
            lpart[3 * BB * NT + row];
  const float inv = 1.f / l;
  float4 v0 = ((const float4*)(outpart + 0 * NP))[idx];
  float4 v1 = ((const float4*)(outpart + 1 * NP))[idx];
  float4 v2 = ((const float4*)(outpart + 2 * NP))[idx];
  float4 v3 = ((const float4*)(outpart + 3 * NP))[idx];
  float4 o;
  o.x = leaky_max((v0.x + v1.x + v2.x + v3.x) * inv, OUT_SLOPE);
  o.y = leaky_max((v0.y + v1.y + v2.y + v3.y) * inv, OUT_SLOPE);
  o.z = leaky_max((v0.z + v1.z + v2.z + v3.z) * inv, OUT_SLOPE);
  o.w = leaky_max((v0.w + v1.w + v2.w + v3.w) * inv, OUT_SLOPE);
  ((float4*)out)[idx] = o;
}

extern "C" void kernel_launch(void* const* d_in, const int* in_sizes, int n_in,
                              void* d_out, int out_size, void* d_ws, size_t ws_size,
                              hipStream_t stream) {
  const float* h   = (const float*)d_in[0];  // [B, Nt, Ft]
  const float* ctx = (const float*)d_in[1];  // [B, Ns, Fs]
  const int*   adj = (const int*)d_in[2];    // [B, Nt, Ns]
  const float* Ws  = (const float*)d_in[3];  // [Fs, Fo]
  const float* Wt  = (const float*)d_in[4];  // [Ft, Fo]
  const float* a   = (const float*)d_in[5];  // [2*Fo, 1]
  float* out = (float*)d_out;                // [B, Nt, Fo] fp32
  float* ws = (float*)d_ws;

  // workspace layout (floats), total ~19.3 MB; every element written before read
  float* outpart = ws;                               // JSPLIT * B*NT*FO = 4,194,304
  float* lpart   = outpart + (size_t)JSPLIT * BB * NT * FO;  // JSPLIT * B*NT = 65,536
  float* tvec    = lpart + (size_t)JSPLIT * BB * NT;  // 16384
  float* svec    = tvec + BB * NS;                    // 16384
  float* tmax    = svec + BB * NS;                    // 4
  short* vT      = (short*)(tmax + 4);                // B*FO*NS bf16 = 2 MB

  k_pre<<<(BB * NT) / 64, 256, 0, stream>>>(Wt, a, h, tvec);
  k_tmax<<<BB, 256, 0, stream>>>(tvec, tmax);
  k_wsctx<<<(BB * NS) / 16, 256, 0, stream>>>(ctx, Ws, a, vT, svec);
  k_part<<<(BB * NT / 64) * JSPLIT, 256, 0, stream>>>(adj, vT, svec, tvec, tmax,
                                                      outpart, lpart);
  k_fin<<<(BB * NT * FO / 4) / 256, 256, 0, stream>>>(outpart, lpart, out);
}

// Round 5
// 492.094 us; speedup vs baseline: 1.0488x; 1.0488x over previous
//
#include <hip/hip_runtime.h>

// Problem constants (fixed by the reference)
#define BB 4
#define NS 4096
#define NT 4096
#define FS 256
#define FT 256
#define FO 64
#define ALPHA 0.2f
#define OUT_SLOPE 0.01f
#define JSPLIT 4   // j-range split across blocks (partials combined in k_fin)

typedef __attribute__((ext_vector_type(8))) short short8;
typedef __attribute__((ext_vector_type(4))) float floatx4;

__device__ __forceinline__ float leaky_max(float x, float s) { return fmaxf(x, s * x); }

// fp32 -> bf16 round-to-nearest-even
__device__ __forceinline__ short f2bf(float x) {
  union { float f; unsigned u; } c; c.f = x;
  unsigned r = c.u + 0x7fffu + ((c.u >> 16) & 1u);
  return (short)(r >> 16);
}

// Fused: wa[f] = Wt[f,:] @ a[64:] (redundant per block, LDS) then
// t[row] = h[row,:] @ wa.  256 blocks x 64 rows.
__global__ __launch_bounds__(256) void k_pre(const float* __restrict__ Wt,
                                             const float* __restrict__ a,
                                             const float* __restrict__ h,
                                             float* __restrict__ tvec) {
  __shared__ __align__(16) float wa[256];
  const int tid = threadIdx.x;
  {
    float acc = 0.f;
#pragma unroll 8
    for (int o = 0; o < FO; ++o) acc += Wt[tid * FO + o] * a[FO + o];
    wa[tid] = acc;
  }
  __syncthreads();
  const int lane = tid & 63, wv = tid >> 6;
  const float4 w4 = ((const float4*)wa)[lane];
#pragma unroll 4
  for (int rr = 0; rr < 16; ++rr) {
    const int row = blockIdx.x * 64 + wv * 16 + rr;
    const float4 hv = ((const float4*)(h + (size_t)row * FT))[lane];
    float acc = hv.x * w4.x + hv.y * w4.y + hv.z * w4.z + hv.w * w4.w;
#pragma unroll
    for (int off = 32; off; off >>= 1) acc += __shfl_down(acc, off);
    if (lane == 0) tvec[row] = acc;
  }
}

// per-batch max of t (softmax shift; any per-row-valid upper bound works)
__global__ __launch_bounds__(256) void k_tmax(const float* __restrict__ tvec,
                                              float* __restrict__ tmax) {
  __shared__ float red[256];
  int b = blockIdx.x, tid = threadIdx.x;
  float m = -3.0e38f;
  for (int j = tid; j < NS; j += 256) m = fmaxf(m, tvec[b * NS + j]);
  red[tid] = m;
  __syncthreads();
  for (int s = 128; s; s >>= 1) {
    if (tid < s) red[tid] = fmaxf(red[tid], red[tid + s]);
    __syncthreads();
  }
  if (tid == 0) tmax[b] = red[0];
}

// Ws_ctx = ctx @ Ws; writes TRANSPOSED bf16 vT[b][f][row] (MFMA B-operand feed)
// and s[row] = Ws_ctx[row,:] @ a[:64].  One wave per 4 rows, 64 lanes = f.
__global__ __launch_bounds__(256) void k_wsctx(const float* __restrict__ ctx,
                                               const float* __restrict__ Ws,
                                               const float* __restrict__ a,
                                               short* __restrict__ vT,
                                               float* __restrict__ svec) {
  const int f = threadIdx.x & 63, wave = threadIdx.x >> 6;
  const int row0 = blockIdx.x * 16 + wave * 4;  // global row in [0, B*NS)
  const float4* c0 = (const float4*)(ctx + (size_t)(row0 + 0) * FS);
  const float4* c1 = (const float4*)(ctx + (size_t)(row0 + 1) * FS);
  const float4* c2 = (const float4*)(ctx + (size_t)(row0 + 2) * FS);
  const float4* c3 = (const float4*)(ctx + (size_t)(row0 + 3) * FS);
  float r0 = 0.f, r1 = 0.f, r2 = 0.f, r3 = 0.f;
#pragma unroll 2
  for (int k4 = 0; k4 < FS / 4; ++k4) {
    const float w0 = Ws[(k4 * 4 + 0) * FO + f];
    const float w1 = Ws[(k4 * 4 + 1) * FO + f];
    const float w2 = Ws[(k4 * 4 + 2) * FO + f];
    const float w3 = Ws[(k4 * 4 + 3) * FO + f];
    float4 x;
    x = c0[k4]; r0 += x.x * w0 + x.y * w1 + x.z * w2 + x.w * w3;
    x = c1[k4]; r1 += x.x * w0 + x.y * w1 + x.z * w2 + x.w * w3;
    x = c2[k4]; r2 += x.x * w0 + x.y * w1 + x.z * w2 + x.w * w3;
    x = c3[k4]; r3 += x.x * w0 + x.y * w1 + x.z * w2 + x.w * w3;
  }
  const int b = row0 >> 12;             // NS = 4096 rows per batch
  const int rloc = row0 & (NS - 1);
  short* vp = vT + ((size_t)b * FO + f) * NS + rloc;
  vp[0] = f2bf(r0); vp[1] = f2bf(r1); vp[2] = f2bf(r2); vp[3] = f2bf(r3);

  const float af = a[f];
  float s0 = r0 * af, s1 = r1 * af, s2 = r2 * af, s3 = r3 * af;
#pragma unroll
  for (int off = 32; off; off >>= 1) {
    s0 += __shfl_down(s0, off);
    s1 += __shfl_down(s1, off);
    s2 += __shfl_down(s2, off);
    s3 += __shfl_down(s3, off);
  }
  if (f == 0) {
    svec[row0 + 0] = s0;
    svec[row0 + 1] = s1;
    svec[row0 + 2] = s2;
    svec[row0 + 3] = s3;
  }
}

// MFMA partial attention: each wave owns 16 rows, computes w on the fly
// (A-frag = 8 consecutive j per lane, generated in-register; no LDS),
// B-frag = 16B contiguous load from vT.  Plain cached adj loads: the harness's
// per-iter input restore leaves adj L3-resident (R2 FETCH=135MB < 268MB adj);
// nontemporal loads forfeited that and regressed 30us in R4.
__global__ __launch_bounds__(256) void k_part(const int* __restrict__ adj,
                                              const short* __restrict__ vT,
                                              const float* __restrict__ svec,
                                              const float* __restrict__ tvec,
                                              const float* __restrict__ tmax,
                                              float* __restrict__ outpart,
                                              float* __restrict__ lpart) {
  const int lane = threadIdx.x & 63;
  const int wv = threadIdx.x >> 6;   // 0..3
  const int m = lane & 15;           // A row within 16 / B,D col (f within 16)
  const int q = lane >> 4;           // quad: k-offset q*8

  const int tile = blockIdx.x >> 2;      // 256 row-tiles of 64
  const int js = blockIdx.x & (JSPLIT - 1);
  const int b = tile >> 6;               // 64 tiles per batch
  const int i0 = (tile & 63) * 64;
  const int jbase = js * (NS / JSPLIT);

  const int r = i0 + wv * 16 + m;        // this lane's target row (within batch)
  const float sr = svec[b * NS + r];
  const float cr = leaky_max(sr + tmax[b], ALPHA);

  const int* arow = adj + ((size_t)(b * NT) + r) * NS + jbase;
  const float* tp = tvec + b * NS + jbase;
  const short* vp0 = vT + ((size_t)b * FO + m) * NS + jbase;  // + ft*16*NS

  floatx4 acc0 = {0.f, 0.f, 0.f, 0.f};
  floatx4 acc1 = {0.f, 0.f, 0.f, 0.f};
  floatx4 acc2 = {0.f, 0.f, 0.f, 0.f};
  floatx4 acc3 = {0.f, 0.f, 0.f, 0.f};
  float lsum = 0.f;

#pragma unroll 2
  for (int jc = 0; jc < (NS / JSPLIT) / 32; ++jc) {
    const int j0 = jc * 32 + q * 8;
    const int4 a0 = *(const int4*)(arow + j0);
    const int4 a1 = *(const int4*)(arow + j0 + 4);
    const float4 t0 = *(const float4*)(tp + j0);
    const float4 t1 = *(const float4*)(tp + j0 + 4);

    float w[8];
    w[0] = (a0.x > 0) ? __expf(leaky_max(sr + t0.x, ALPHA) - cr) : 0.f;
    w[1] = (a0.y > 0) ? __expf(leaky_max(sr + t0.y, ALPHA) - cr) : 0.f;
    w[2] = (a0.z > 0) ? __expf(leaky_max(sr + t0.z, ALPHA) - cr) : 0.f;
    w[3] = (a0.w > 0) ? __expf(leaky_max(sr + t0.w, ALPHA) - cr) : 0.f;
    w[4] = (a1.x > 0) ? __expf(leaky_max(sr + t1.x, ALPHA) - cr) : 0.f;
    w[5] = (a1.y > 0) ? __expf(leaky_max(sr + t1.y, ALPHA) - cr) : 0.f;
    w[6] = (a1.z > 0) ? __expf(leaky_max(sr + t1.z, ALPHA) - cr) : 0.f;
    w[7] = (a1.w > 0) ? __expf(leaky_max(sr + t1.w, ALPHA) - cr) : 0.f;

    lsum += ((w[0] + w[1]) + (w[2] + w[3])) + ((w[4] + w[5]) + (w[6] + w[7]));

    short8 af;
#pragma unroll
    for (int i = 0; i < 8; ++i) af[i] = f2bf(w[i]);

    const short8 bf0 = *(const short8*)(vp0 + 0 * 16 * NS + j0);
    const short8 bf1 = *(const short8*)(vp0 + 1 * 16 * NS + j0);
    const short8 bf2 = *(const short8*)(vp0 + 2 * 16 * NS + j0);
    const short8 bf3 = *(const short8*)(vp0 + 3 * 16 * NS + j0);
    acc0 = __builtin_amdgcn_mfma_f32_16x16x32_bf16(af, bf0, acc0, 0, 0, 0);
    acc1 = __builtin_amdgcn_mfma_f32_16x16x32_bf16(af, bf1, acc1, 0, 0, 0);
    acc2 = __builtin_amdgcn_mfma_f32_16x16x32_bf16(af, bf2, acc2, 0, 0, 0);
    acc3 = __builtin_amdgcn_mfma_f32_16x16x32_bf16(af, bf3, acc3, 0, 0, 0);
  }

  // denominator partial: reduce lsum over the 4 quads holding the same row m
  float v = lsum;
  v += __shfl_down(v, 32);
  v += __shfl_down(v, 16);
  if (lane < 16) lpart[(size_t)js * BB * NT + (size_t)b * NT + i0 + wv * 16 + m] = v;

  // numerator partial: D layout col=lane&15, row=(lane>>4)*4+reg
  float* op = outpart + (size_t)js * BB * NT * FO +
              ((size_t)(b * NT) + i0 + wv * 16 + q * 4) * FO + m;
#pragma unroll
  for (int reg = 0; reg < 4; ++reg) {
    op[(size_t)reg * FO + 0 * 16] = acc0[reg];
    op[(size_t)reg * FO + 1 * 16] = acc1[reg];
    op[(size_t)reg * FO + 2 * 16] = acc2[reg];
    op[(size_t)reg * FO + 3 * 16] = acc3[reg];
  }
}

// out[i,f] = leaky( (sum_js outpart) / (sum_js lpart), 0.01 ), float4-vectorized
__global__ __launch_bounds__(256) void k_fin(const float* __restrict__ outpart,
                                             const float* __restrict__ lpart,
                                             float* __restrict__ out) {
  const size_t NP = (size_t)BB * NT * FO;   // floats per partial
  const int idx = blockIdx.x * 256 + threadIdx.x;   // float4 index
  const int row = idx >> 4;                          // 16 float4 per row
  float l = lpart[row] + lpart[BB * NT + row] + lpart[2 * BB * NT + row] +
            lpart[3 * BB * NT + row];
  const float inv = 1.f / l;
  float4 v0 = ((const float4*)(outpart + 0 * NP))[idx];
  float4 v1 = ((const float4*)(outpart + 1 * NP))[idx];
  float4 v2 = ((const float4*)(outpart + 2 * NP))[idx];
  float4 v3 = ((const float4*)(outpart + 3 * NP))[idx];
  float4 o;
  o.x = leaky_max((v0.x + v1.x + v2.x + v3.x) * inv, OUT_SLOPE);
  o.y = leaky_max((v0.y + v1.y + v2.y + v3.y) * inv, OUT_SLOPE);
  o.z = leaky_max((v0.z + v1.z + v2.z + v3.z) * inv, OUT_SLOPE);
  o.w = leaky_max((v0.w + v1.w + v2.w + v3.w) * inv, OUT_SLOPE);
  ((float4*)out)[idx] = o;
}

extern "C" void kernel_launch(void* const* d_in, const int* in_sizes, int n_in,
                              void* d_out, int out_size, void* d_ws, size_t ws_size,
                              hipStream_t stream) {
  const float* h   = (const float*)d_in[0];  // [B, Nt, Ft]
  const float* ctx = (const float*)d_in[1];  // [B, Ns, Fs]
  const int*   adj = (const int*)d_in[2];    // [B, Nt, Ns]
  const float* Ws  = (const float*)d_in[3];  // [Fs, Fo]
  const float* Wt  = (const float*)d_in[4];  // [Ft, Fo]
  const float* a   = (const float*)d_in[5];  // [2*Fo, 1]
  float* out = (float*)d_out;                // [B, Nt, Fo] fp32
  float* ws = (float*)d_ws;

  // workspace layout (floats), total ~19.3 MB; every element written before read
  float* outpart = ws;                               // JSPLIT * B*NT*FO = 4,194,304
  float* lpart   = outpart + (size_t)JSPLIT * BB * NT * FO;  // JSPLIT * B*NT = 65,536
  float* tvec    = lpart + (size_t)JSPLIT * BB * NT;  // 16384
  float* svec    = tvec + BB * NS;                    // 16384
  float* tmax    = svec + BB * NS;                    // 4
  short* vT      = (short*)(tmax + 4);                // B*FO*NS bf16 = 2 MB

  k_pre<<<(BB * NT) / 64, 256, 0, stream>>>(Wt, a, h, tvec);
  k_tmax<<<BB, 256, 0, stream>>>(tvec, tmax);
  k_wsctx<<<(BB * NS) / 16, 256, 0, stream>>>(ctx, Ws, a, vT, svec);
  k_part<<<(BB * NT / 64) * JSPLIT, 256, 0, stream>>>(adj, vT, svec, tvec, tmax,
                                                      outpart, lpart);
  k_fin<<<(BB * NT * FO / 4) / 256, 256, 0, stream>>>(outpart, lpart, out);
}